// Round 11
// baseline (932.246 us; speedup 1.0000x reference)
//
#include <hip/hip_runtime.h>

typedef __bf16 bf16_t;
typedef bf16_t bf16x2_t __attribute__((ext_vector_type(2)));
typedef bf16_t bf16x8_t __attribute__((ext_vector_type(8)));
typedef float  f32x4_t  __attribute__((ext_vector_type(4)));
typedef float  f32x2_t  __attribute__((ext_vector_type(2)));
typedef unsigned int u32x4_t __attribute__((ext_vector_type(4)));

#define RCHUNK 4096
#define MFMA16(a, b, c) __builtin_amdgcn_mfma_f32_16x16x32_bf16((a), (b), (c), 0, 0, 0)

// ---------------------------------------------------------------------------
// Weight packing: W[t][k0+k][n] (f32, row-stride 128) -> bf16 MFMA-B-fragment
// order: out[((t*KB+kb)*8+nb)*512 + l*8 + j] = W[t][k0+kb*32+(l>>4)*8+j][nb*16+(l&15)]
// ---------------------------------------------------------------------------
__global__ void pack_w_kernel(const float* __restrict__ W, bf16_t* __restrict__ out,
                              int T, int Ksrc, int k0, int KB)
{
  int total = T * KB * 8 * 512;
  for (int idx = blockIdx.x * blockDim.x + threadIdx.x; idx < total;
       idx += gridDim.x * blockDim.x) {
    int j  = idx & 7;
    int l  = (idx >> 3) & 63;
    int nb = (idx >> 9) & 7;
    int r  = idx >> 12;
    int kb = r % KB;
    int t  = r / KB;
    int k = k0 + kb * 32 + ((l >> 4) << 3) + j;
    int n = nb * 16 + (l & 15);
    out[idx] = (bf16_t)W[((size_t)t * Ksrc + k) * 128 + n];
  }
}

// ---------------------------------------------------------------------------
// Stable counting-sort rank/perm over a small type alphabet T.
// ---------------------------------------------------------------------------
template <int T>
__global__ void count_types_kernel(const int* __restrict__ tv, int n,
                                   int* __restrict__ blkcnt)
{
  __shared__ int cnt[T];
  int tid = threadIdx.x, b = blockIdx.x;
  if (tid < T) cnt[tid] = 0;
  __syncthreads();
  int lo = b * RCHUNK, hi = min(n, lo + RCHUNK);
  int loc[T];
#pragma unroll
  for (int t = 0; t < T; ++t) loc[t] = 0;
  for (int i = lo + tid; i < hi; i += 256) {
    int tq = tv[i];
#pragma unroll
    for (int t = 0; t < T; ++t) loc[t] += (tq == t);
  }
#pragma unroll
  for (int t = 0; t < T; ++t)
    if (loc[t]) atomicAdd(&cnt[t], loc[t]);
  __syncthreads();
  if (tid < T) blkcnt[b * T + tid] = cnt[tid];
}

template <int T>
__global__ void scan_blocks_kernel(const int* __restrict__ blkcnt, int nblocks,
                                   int* __restrict__ blkbase)
{
  __shared__ int sh[256];
  __shared__ int tot[T];
  int tid = threadIdx.x;
  int myc[T], excl[T];
#pragma unroll
  for (int t = 0; t < T; ++t) myc[t] = (tid < nblocks) ? blkcnt[tid * T + t] : 0;
#pragma unroll
  for (int t = 0; t < T; ++t) {
    sh[tid] = myc[t];
    __syncthreads();
    for (int off = 1; off < 256; off <<= 1) {
      int v = (tid >= off) ? sh[tid - off] : 0;
      __syncthreads();
      sh[tid] += v;
      __syncthreads();
    }
    excl[t] = sh[tid] - myc[t];
    if (tid == 255) tot[t] = sh[255];
    __syncthreads();
  }
  if (tid < nblocks) {
    int run = 0;
#pragma unroll
    for (int t = 0; t < T; ++t) {
      blkbase[tid * T + t] = run + excl[t];
      run += tot[t];
    }
  }
}

template <int T>
__global__ void write_ranks_kernel(const int* __restrict__ tv, int n,
                                   const int* __restrict__ blkbase,
                                   int* __restrict__ rank, int* __restrict__ perm)
{
  __shared__ int sh[256];
  int tid = threadIdx.x, b = blockIdx.x;
  int lo = b * RCHUNK + tid * 16;
  int tvq[16];
  int myc[T];
#pragma unroll
  for (int t = 0; t < T; ++t) myc[t] = 0;
#pragma unroll
  for (int q = 0; q < 16; ++q) {
    int i = lo + q;
    int tq = (i < n) ? tv[i] : -1;
    tvq[q] = tq;
#pragma unroll
    for (int t = 0; t < T; ++t) myc[t] += (tq == t);
  }
  int mybase[T];
#pragma unroll
  for (int t = 0; t < T; ++t) {
    sh[tid] = myc[t];
    __syncthreads();
    for (int off = 1; off < 256; off <<= 1) {
      int v = (tid >= off) ? sh[tid - off] : 0;
      __syncthreads();
      sh[tid] += v;
      __syncthreads();
    }
    mybase[t] = blkbase[b * T + t] + sh[tid] - myc[t];
    __syncthreads();
  }
#pragma unroll
  for (int q = 0; q < 16; ++q) {
    int tq = tvq[q];
    if (tq < 0) continue;
    int r = 0;
#pragma unroll
    for (int t = 0; t < T; ++t)
      if (tq == t) { r = mybase[t]; mybase[t] = r + 1; }
    rank[lo + q] = r;
    perm[r] = lo + q;
  }
}

// ---------------------------------------------------------------------------
// (type, dst[j]) keys: key[pos] = t(pos)*N + dst[rank[pos]]; multi-block scan;
// meta build in POS order: meta4[pos]={e,src,dst,slot}, jmap[slot]=j.
// ---------------------------------------------------------------------------
__global__ void key_hist_kernel(const int* __restrict__ rank,
                                const int* __restrict__ dst,
                                const int* __restrict__ tb, int E, int Nn,
                                int* __restrict__ key, int* __restrict__ khist)
{
  int pos = blockIdx.x * blockDim.x + threadIdx.x;
  if (pos < E) {
    int t = (pos >= tb[1]) + (pos >= tb[2]);
    int k = t * Nn + dst[rank[pos]];
    key[pos] = k;
    atomicAdd(&khist[k], 1);
  }
}

__global__ __launch_bounds__(1024) void mscan_pass1(const int* __restrict__ h,
                                                    int n, int* __restrict__ part)
{
  __shared__ int sh[1024];
  int tid = threadIdx.x;
  int i0 = blockIdx.x * 4096 + tid * 4;
  int s = 0;
#pragma unroll
  for (int q = 0; q < 4; ++q) { int i = i0 + q; s += (i < n) ? h[i] : 0; }
  sh[tid] = s;
  __syncthreads();
  for (int off = 512; off > 0; off >>= 1) {
    if (tid < off) sh[tid] += sh[tid + off];
    __syncthreads();
  }
  if (tid == 0) part[blockIdx.x] = sh[0];
}

__global__ __launch_bounds__(1024) void mscan_pass2(int* __restrict__ part, int nb)
{
  __shared__ int sh[1024];
  int tid = threadIdx.x;
  int v = (tid < nb) ? part[tid] : 0;
  sh[tid] = v;
  __syncthreads();
  for (int off = 1; off < 1024; off <<= 1) {
    int u = (tid >= off) ? sh[tid - off] : 0;
    __syncthreads();
    sh[tid] += u;
    __syncthreads();
  }
  if (tid < nb) part[tid] = sh[tid] - v;
  if (tid == 1023) part[nb] = sh[1023];
}

__global__ __launch_bounds__(1024) void mscan_pass3(
    const int* __restrict__ h, int n, const int* __restrict__ part, int nb,
    int* __restrict__ offs, int* __restrict__ cur)
{
  __shared__ int sh[1024];
  int tid = threadIdx.x;
  int i0 = blockIdx.x * 4096 + tid * 4;
  int v[4];
  int s = 0;
#pragma unroll
  for (int q = 0; q < 4; ++q) { int i = i0 + q; v[q] = (i < n) ? h[i] : 0; s += v[q]; }
  sh[tid] = s;
  __syncthreads();
  for (int off = 1; off < 1024; off <<= 1) {
    int u = (tid >= off) ? sh[tid - off] : 0;
    __syncthreads();
    sh[tid] += u;
    __syncthreads();
  }
  int run = part[blockIdx.x] + sh[tid] - s;
#pragma unroll
  for (int q = 0; q < 4; ++q) {
    int i = i0 + q;
    if (i < n) { offs[i] = run; cur[i] = run; run += v[q]; }
  }
  if (blockIdx.x == 0 && tid == 0) offs[n] = part[nb];
}

__global__ void build_meta_edge_kernel(const int* __restrict__ key,
                                       const int* __restrict__ perm,
                                       const int* __restrict__ rank,
                                       const int* __restrict__ src,
                                       const int* __restrict__ dst,
                                       int* __restrict__ kcursor,
                                       int4* __restrict__ meta4,
                                       int* __restrict__ jmap, int E)
{
  int pos = blockIdx.x * blockDim.x + threadIdx.x;
  if (pos < E) {
    int slot = atomicAdd(&kcursor[key[pos]], 1);
    int e = perm[pos];
    int4 m;
    m.x = e; m.y = src[e]; m.z = dst[e]; m.w = slot;
    meta4[pos] = m;
    jmap[slot] = rank[pos];
  }
}

__global__ void gather_meta_node_kernel(const int* __restrict__ perm,
                                        const int* __restrict__ rank,
                                        int4* __restrict__ meta4, int N)
{
  int i = blockIdx.x * blockDim.x + threadIdx.x;
  if (i < N) {
    int e = perm[i];
    int4 m;
    m.x = e; m.y = e; m.z = e; m.w = rank[i];
    meta4[i] = m;
  }
}

// ---------------------------------------------------------------------------
// Fused aggregate + scatter: streams slot_buf (bf16, (type,dst)-grouped);
// writes out_ef[jmap[slot]] (f32, full 512B rows) and agg[n] (f32).
// NON-TEMPORAL on the streaming slot_buf reads and out_ef writes so the L3
// keeps the P tables / agg warm for the other kernels.
// ---------------------------------------------------------------------------
__global__ __launch_bounds__(256) void aggregate_scatter_kernel(
    const bf16_t* __restrict__ slot_buf, const int* __restrict__ koffs,
    const int* __restrict__ jmap, float* __restrict__ out_ef,
    float* __restrict__ agg, int Nn)
{
  int gw = (blockIdx.x * 256 + threadIdx.x) >> 6;
  int l = threadIdx.x & 63;
  int nw = (gridDim.x * 256) >> 6;
  for (int n = gw; n < Nn; n += nw) {
    float sx = 0.f, sy = 0.f;
#pragma unroll
    for (int t = 0; t < 3; ++t) {
      int k = t * Nn + n;
      int lo = koffs[k], hi = koffs[k + 1];
      int q = lo;
      for (; q + 1 < hi; q += 2) {
        bf16x2_t v0 = __builtin_nontemporal_load(
            (const bf16x2_t*)(slot_buf + (size_t)q * 128 + l * 2));
        bf16x2_t v1 = __builtin_nontemporal_load(
            (const bf16x2_t*)(slot_buf + (size_t)(q + 1) * 128 + l * 2));
        int j0 = jmap[q], j1 = jmap[q + 1];
        float a0 = (float)v0[0], a1 = (float)v0[1];
        float b0 = (float)v1[0], b1 = (float)v1[1];
        sx += a0 + b0; sy += a1 + b1;
        f32x2_t o0; o0[0] = a0; o0[1] = a1;
        f32x2_t o1; o1[0] = b0; o1[1] = b1;
        __builtin_nontemporal_store(o0, (f32x2_t*)(out_ef + (size_t)j0 * 128 + l * 2));
        __builtin_nontemporal_store(o1, (f32x2_t*)(out_ef + (size_t)j1 * 128 + l * 2));
      }
      if (q < hi) {
        bf16x2_t v0 = __builtin_nontemporal_load(
            (const bf16x2_t*)(slot_buf + (size_t)q * 128 + l * 2));
        int j0 = jmap[q];
        float a0 = (float)v0[0], a1 = (float)v0[1];
        sx += a0; sy += a1;
        f32x2_t o0; o0[0] = a0; o0[1] = a1;
        __builtin_nontemporal_store(o0, (f32x2_t*)(out_ef + (size_t)j0 * 128 + l * 2));
      }
    }
    f32x2_t o; o[0] = sx; o[1] = sy;
    *(f32x2_t*)(agg + (size_t)n * 128 + l * 2) = o;
  }
}

// ---------------------------------------------------------------------------
// P precompute: one block per 64-node tile computes ALL 8 projections.
// ---------------------------------------------------------------------------
__global__ __launch_bounds__(256, 4) void precompute_p2_kernel(
    const float* __restrict__ nf,
    const bf16_t* __restrict__ pW1s, const bf16_t* __restrict__ pW1d,
    const bf16_t* __restrict__ pWn1b,
    bf16_t* __restrict__ Ps, bf16_t* __restrict__ Pd, bf16_t* __restrict__ Pn,
    int Nn)
{
  __shared__ char Ysm[16384];
  const int tid = threadIdx.x, l = tid & 63, w = tid >> 6;
  const int rb = (w >> 1) * 32, cb = (w & 1) * 64, l15 = l & 15;
  const int koff = (l >> 4) << 3;
  const int base = blockIdx.x * 64;

  const int r0 = min(base + rb + l15, Nn - 1);
  const int r1 = min(base + rb + l15 + 16, Nn - 1);
  const float* q0 = nf + (size_t)r0 * 128 + koff;
  const float* q1 = nf + (size_t)r1 * 128 + koff;
  bf16x8_t a0[4], a1[4];
#pragma unroll
  for (int kb = 0; kb < 4; ++kb) {
    f32x4_t u0 = ((const f32x4_t*)(q0 + kb * 32))[0];
    f32x4_t u1 = ((const f32x4_t*)(q0 + kb * 32))[1];
    f32x4_t u2 = ((const f32x4_t*)(q1 + kb * 32))[0];
    f32x4_t u3 = ((const f32x4_t*)(q1 + kb * 32))[1];
#pragma unroll
    for (int z = 0; z < 4; ++z) {
      a0[kb][z] = (bf16_t)u0[z]; a0[kb][4 + z] = (bf16_t)u1[z];
      a1[kb][z] = (bf16_t)u2[z]; a1[kb][4 + z] = (bf16_t)u3[z];
    }
  }

  for (int which = 0; which < 8; ++which) {
    const bf16_t* pB; bf16_t* po;
    if (which < 3)      { pB = pW1s + which * 16384;        po = Ps + (size_t)which * Nn * 128; }
    else if (which < 6) { pB = pW1d + (which - 3) * 16384;  po = Pd + (size_t)(which - 3) * Nn * 128; }
    else                { pB = pWn1b + (which - 6) * 16384; po = Pn + (size_t)(which - 6) * Nn * 128; }
    const bf16x8_t* wg = (const bf16x8_t*)pB;

    f32x4_t acc[2][4];
#pragma unroll
    for (int m = 0; m < 2; ++m)
#pragma unroll
      for (int n = 0; n < 4; ++n) acc[m][n] = (f32x4_t){0.f, 0.f, 0.f, 0.f};
#pragma unroll
    for (int kb = 0; kb < 4; ++kb) {
      bf16x8_t bfr[4];
#pragma unroll
      for (int n = 0; n < 4; ++n)
        bfr[n] = wg[(size_t)((kb * 8 + (cb >> 4) + n) * 64 + l)];
#pragma unroll
      for (int n = 0; n < 4; ++n) {
        acc[0][n] = MFMA16(a0[kb], bfr[n], acc[0][n]);
        acc[1][n] = MFMA16(a1[kb], bfr[n], acc[1][n]);
      }
    }

    __syncthreads();
#pragma unroll
    for (int n = 0; n < 4; ++n) {
      int col = cb + 16 * n + l15;
#pragma unroll
      for (int m = 0; m < 2; ++m)
#pragma unroll
        for (int jj = 0; jj < 4; ++jj) {
          int row = rb + 16 * m + ((l >> 4) << 2) + jj;
          *(bf16_t*)(Ysm + row * 256 + ((col * 2) ^ ((row & 7) << 4))) =
              (bf16_t)acc[m][n][jj];
        }
    }
    __syncthreads();
    {
      int row = tid >> 2, cpart = tid & 3;
      int node = base + row;
      if (node < Nn) {
        bf16_t* dstp = po + (size_t)node * 128 + cpart * 32;
#pragma unroll
        for (int q = 0; q < 4; ++q) {
          int c = cpart * 4 + q;
          *(u32x4_t*)(dstp + q * 8) = *(const u32x4_t*)(
              Ysm + row * 256 + ((c * 16) ^ ((row & 7) << 4)));
        }
      }
    }
  }
}

// ---------------------------------------------------------------------------
// mlp8nt: R8's fused per-type 2-layer MLP (pos-order tiles, W1 in LDS, W2 in
// regs, Psum in-place in Hsm, coalesced slot_buf writes) with NON-TEMPORAL
// hints on the streaming accesses (EDGE feat reads, slot_buf writes) so the
// L3 retains the randomly-gathered Ps/Pd tables.
// ---------------------------------------------------------------------------
template <int T, bool EDGE>
__global__ __launch_bounds__(256, 3) void mlp8nt_kernel(
    const float* __restrict__ feat,
    const int4* __restrict__ meta4,
    const int* __restrict__ tbase,
    const bf16_t* __restrict__ pW1, const float* __restrict__ b1,
    const bf16_t* __restrict__ pW2, const float* __restrict__ b2,
    const bf16_t* __restrict__ P1, const bf16_t* __restrict__ P2, int pnodes,
    float* __restrict__ out, bf16_t* __restrict__ slot_out, int Ntot)
{
  __shared__ char Wsm[32768];
  __shared__ char Hsm[16384];
  __shared__ int sm_e[64], sm_sl[64], sm_s0[64], sm_s1[64];

  const int tid = threadIdx.x;
  const int l = tid & 63, w = tid >> 6;
  const int rb = (w >> 1) * 32, cb = (w & 1) * 64;
  const int l15 = l & 15;
  const int koff = (l >> 4) << 3;

  const int s0 = tbase[0];
  const int s1 = (T > 1) ? tbase[1] : Ntot;
  const int s2 = (T > 2) ? tbase[2] : Ntot;
  const int e0t = (T > 1) ? s1 : Ntot;
  const int e1t = (T > 2) ? s2 : Ntot;
  const int c0 = (e0t - s0 + 63) >> 6;
  const int c1 = (T > 1) ? ((e1t - s1 + 63) >> 6) : 0;
  const int c2 = (T > 2) ? ((Ntot - s2 + 63) >> 6) : 0;
  const int cum1 = c0, cum2 = c0 + c1, total = cum2 + c2;

  const int tpb = (total + gridDim.x - 1) / gridDim.x;
  const int pt0 = blockIdx.x * tpb;
  const int pt1 = min(total, pt0 + tpb);

  int cur_t = -1;
  bf16x8_t w2r[16];
  float bh[4], bo[4];

  for (int pt = pt0; pt < pt1; ++pt) {
    const int t = (pt < cum1) ? 0 : ((pt < cum2) ? 1 : 2);
    const int tstart = (t == 0) ? s0 : ((t == 1) ? s1 : s2);
    const int tend = (t == 0) ? e0t : ((t == 1) ? e1t : Ntot);
    const int i = pt - ((t == 0) ? 0 : ((t == 1) ? cum1 : cum2));
    const int pbase = tstart + (i << 6);

    __syncthreads();                   // B0: prev tile fully consumed
    if (tid < 64) {
      int pos = pbase + tid;
      if (pos < tend) {
        int4 m = meta4[pos];
        sm_e[tid] = m.x;
        sm_sl[tid] = m.w;              // EDGE: slot; NODE: j
        if (EDGE) { sm_s0[tid] = m.y; sm_s1[tid] = m.z; }
      } else {
        sm_e[tid] = 0; sm_sl[tid] = -1;
        if (EDGE) { sm_s0[tid] = 0; sm_s1[tid] = 0; }
      }
    }
    __syncthreads();                   // B1: meta visible

    // ---- burst A: lane's full-K slice of 2 rows (nontemporal for EDGE) ----
    const int ar0 = rb + l15, ar1 = ar0 + 16;
    const float* q0 = feat + (size_t)sm_e[ar0] * 128 + koff;
    const float* q1 = feat + (size_t)sm_e[ar1] * 128 + koff;
    f32x4_t areg[2][4][2];
#pragma unroll
    for (int kb = 0; kb < 4; ++kb) {
      if (EDGE) {
        areg[0][kb][0] = __builtin_nontemporal_load((const f32x4_t*)(q0 + kb * 32));
        areg[0][kb][1] = __builtin_nontemporal_load((const f32x4_t*)(q0 + kb * 32) + 1);
        areg[1][kb][0] = __builtin_nontemporal_load((const f32x4_t*)(q1 + kb * 32));
        areg[1][kb][1] = __builtin_nontemporal_load((const f32x4_t*)(q1 + kb * 32) + 1);
      } else {
        areg[0][kb][0] = ((const f32x4_t*)(q0 + kb * 32))[0];
        areg[0][kb][1] = ((const f32x4_t*)(q0 + kb * 32))[1];
        areg[1][kb][0] = ((const f32x4_t*)(q1 + kb * 32))[0];
        areg[1][kb][1] = ((const f32x4_t*)(q1 + kb * 32))[1];
      }
    }

    // ---- Psum gather -> Hsm IN-PLACE (XOR byte swizzle); temporal (cache!) ----
#pragma unroll
    for (int q = 0; q < 4; ++q) {
      int idx = tid * 4 + q;
      int row = idx >> 4, c8 = idx & 15;
      bf16x8_t s;
      if (EDGE) {
        bf16x8_t u = ((const bf16x8_t*)(P1 + ((size_t)t * pnodes + sm_s0[row]) * 128))[c8];
        bf16x8_t v = ((const bf16x8_t*)(P2 + ((size_t)t * pnodes + sm_s1[row]) * 128))[c8];
#pragma unroll
        for (int z = 0; z < 8; ++z) s[z] = (bf16_t)((float)u[z] + (float)v[z]);
      } else {
        s = ((const bf16x8_t*)(P1 + ((size_t)t * pnodes + sm_e[row]) * 128))[c8];
      }
      *(bf16x8_t*)(Hsm + row * 256 + ((c8 << 4) ^ ((row & 7) << 4))) = s;
    }

    if (t != cur_t) {
      __syncthreads();                 // no wave still reading old Wsm
      {
        const u32x4_t* g = (const u32x4_t*)(pW1 + (size_t)t * 16384);
        u32x4_t* d = (u32x4_t*)Wsm;
#pragma unroll
        for (int q = 0; q < 8; ++q) d[q * 256 + tid] = g[q * 256 + tid];
      }
      {
        const bf16x8_t* g2 = (const bf16x8_t*)pW2;
#pragma unroll
        for (int kb = 0; kb < 4; ++kb)
#pragma unroll
          for (int n = 0; n < 4; ++n)
            w2r[kb * 4 + n] = g2[(size_t)((t * 4 + kb) * 8 + (cb >> 4) + n) * 64 + l];
      }
#pragma unroll
      for (int n = 0; n < 4; ++n) {
        bh[n] = b1[t * 128 + cb + 16 * n + l15];
        bo[n] = b2[t * 128 + cb + 16 * n + l15];
      }
      cur_t = t;
      __syncthreads();
    }

    // ---------------- layer 1 (W1 from LDS) ----------------
    f32x4_t acc[2][4];
#pragma unroll
    for (int m = 0; m < 2; ++m)
#pragma unroll
      for (int n = 0; n < 4; ++n) acc[m][n] = (f32x4_t){0.f, 0.f, 0.f, 0.f};

#pragma unroll
    for (int kb = 0; kb < 4; ++kb) {
      bf16x8_t bfr[4];
#pragma unroll
      for (int n = 0; n < 4; ++n)
        bfr[n] = *(const bf16x8_t*)(Wsm + ((kb * 8 + (cb >> 4) + n) * 64 + l) * 16);
      bf16x8_t a0, a1;
#pragma unroll
      for (int z = 0; z < 4; ++z) {
        a0[z] = (bf16_t)areg[0][kb][0][z]; a0[4 + z] = (bf16_t)areg[0][kb][1][z];
        a1[z] = (bf16_t)areg[1][kb][0][z]; a1[4 + z] = (bf16_t)areg[1][kb][1][z];
      }
#pragma unroll
      for (int n = 0; n < 4; ++n) {
        acc[0][n] = MFMA16(a0, bfr[n], acc[0][n]);
        acc[1][n] = MFMA16(a1, bfr[n], acc[1][n]);
      }
    }

    __syncthreads();                   // B3: Psum staged in Hsm visible
    // h = relu(acc + Psum + b1), in place in Hsm
#pragma unroll
    for (int n = 0; n < 4; ++n) {
      int col = cb + 16 * n + l15;
      int byte = col * 2;
#pragma unroll
      for (int m = 0; m < 2; ++m)
#pragma unroll
        for (int jj = 0; jj < 4; ++jj) {
          int row = rb + 16 * m + ((l >> 4) << 2) + jj;
          char* addr = Hsm + row * 256 + (byte ^ ((row & 7) << 4));
          float pv = (float)*(const bf16_t*)addr;
          float v = acc[m][n][jj] + pv + bh[n];
          v = v > 0.f ? v : 0.f;
          *(bf16_t*)addr = (bf16_t)v;
        }
    }
    __syncthreads();                   // B4: Hsm complete

    // ---------------- layer 2 (W2 in regs) ----------------
    f32x4_t acc2[2][4];
#pragma unroll
    for (int m = 0; m < 2; ++m)
#pragma unroll
      for (int n = 0; n < 4; ++n) acc2[m][n] = (f32x4_t){0.f, 0.f, 0.f, 0.f};

#pragma unroll
    for (int kb = 0; kb < 4; ++kb) {
      int kbyte = kb * 64 + ((l >> 4) << 4);
      int row0 = rb + l15, row1 = row0 + 16;
      bf16x8_t h0 = *(const bf16x8_t*)(Hsm + row0 * 256 + (kbyte ^ ((row0 & 7) << 4)));
      bf16x8_t h1 = *(const bf16x8_t*)(Hsm + row1 * 256 + (kbyte ^ ((row1 & 7) << 4)));
#pragma unroll
      for (int n = 0; n < 4; ++n) {
        acc2[0][n] = MFMA16(h0, w2r[kb * 4 + n], acc2[0][n]);
        acc2[1][n] = MFMA16(h1, w2r[kb * 4 + n], acc2[1][n]);
      }
    }

    // ---------------- epilogue ----------------
    if (EDGE) {
      __syncthreads();                 // B5: all layer-2 Hsm reads done
#pragma unroll
      for (int n = 0; n < 4; ++n) {
        int col = cb + 16 * n + l15;
#pragma unroll
        for (int m = 0; m < 2; ++m)
#pragma unroll
          for (int jj = 0; jj < 4; ++jj) {
            int row = rb + 16 * m + ((l >> 4) << 2) + jj;
            *(bf16_t*)(Hsm + row * 256 + ((col * 2) ^ ((row & 7) << 4))) =
                (bf16_t)(acc2[m][n][jj] + bo[n]);
          }
      }
      __syncthreads();                 // B6: y staged
      {
        int row = tid >> 2, cpart = tid & 3;
        int sl = sm_sl[row];
        if (sl >= 0) {
          char* dstp = (char*)slot_out + (size_t)sl * 256 + cpart * 64;
#pragma unroll
          for (int q = 0; q < 4; ++q) {
            int c = cpart * 4 + q;
            u32x4_t val = *(const u32x4_t*)(
                Hsm + row * 256 + ((c * 16) ^ ((row & 7) << 4)));
            __builtin_nontemporal_store(val, (u32x4_t*)(dstp + q * 16));
          }
        }
      }
    } else {
#pragma unroll
      for (int n = 0; n < 4; ++n) {
        int col = cb + 16 * n + l15;
#pragma unroll
        for (int m = 0; m < 2; ++m)
#pragma unroll
          for (int jj = 0; jj < 4; ++jj) {
            int row = rb + 16 * m + ((l >> 4) << 2) + jj;
            int j = sm_sl[row];
            if (j >= 0) out[(size_t)j * 128 + col] = acc2[m][n][jj] + bo[n];
          }
      }
    }
  }
}

// ---------------------------------------------------------------------------
extern "C" void kernel_launch(void* const* d_in, const int* in_sizes, int n_in,
                              void* d_out, int out_size, void* d_ws, size_t ws_size,
                              hipStream_t stream)
{
  const float* nf    = (const float*)d_in[0];
  const float* ef    = (const float*)d_in[1];
  const int*   src   = (const int*)d_in[2];
  const int*   dst   = (const int*)d_in[3];
  const int*   etype = (const int*)d_in[4];
  const int*   ntype = (const int*)d_in[5];
  const float* Weh   = (const float*)d_in[6];
  const float* beh   = (const float*)d_in[7];
  const float* Weo   = (const float*)d_in[8];
  const float* beo   = (const float*)d_in[9];
  const float* Wnh   = (const float*)d_in[10];
  const float* bnh   = (const float*)d_in[11];
  const float* Wno   = (const float*)d_in[12];
  const float* bno   = (const float*)d_in[13];

  const int E = in_sizes[2];   // 800000
  const int N = in_sizes[5];   // 50000
  const int TE = 3, TN = 2;

  char* ws = (char*)d_ws;
  size_t off = 0;
  auto alloc = [&](size_t bytes) -> char* {
    char* p = ws + off;
    off = (off + bytes + 511) & ~(size_t)511;
    return p;
  };
  bf16_t* pW1e  = (bf16_t*)alloc((size_t)TE * 16384 * 2);
  bf16_t* pW1s  = (bf16_t*)alloc((size_t)TE * 16384 * 2);
  bf16_t* pW1d  = (bf16_t*)alloc((size_t)TE * 16384 * 2);
  bf16_t* pWe2  = (bf16_t*)alloc((size_t)TE * 16384 * 2);
  bf16_t* pWn1a = (bf16_t*)alloc((size_t)TN * 16384 * 2);
  bf16_t* pWn1b = (bf16_t*)alloc((size_t)TN * 16384 * 2);
  bf16_t* pWn2  = (bf16_t*)alloc((size_t)TN * 16384 * 2);
  bf16_t* Ps = (bf16_t*)alloc((size_t)TE * N * 128 * 2);
  bf16_t* Pd = (bf16_t*)alloc((size_t)TE * N * 128 * 2);
  bf16_t* Pn = (bf16_t*)alloc((size_t)TN * N * 128 * 2);
  int* rank_e = (int*)alloc((size_t)E * 4);
  int* perm_e = (int*)alloc((size_t)E * 4);
  int* rank_n = (int*)alloc((size_t)N * 4);
  int* perm_n = (int*)alloc((size_t)N * 4);
  const int NBE = (E + RCHUNK - 1) / RCHUNK;   // 196
  const int NBN = (N + RCHUNK - 1) / RCHUNK;   // 13
  int* blkcnt_e  = (int*)alloc((size_t)NBE * TE * 4);
  int* blkbase_e = (int*)alloc((size_t)NBE * TE * 4);
  int* blkcnt_n  = (int*)alloc((size_t)NBN * TN * 4);
  int* blkbase_n = (int*)alloc((size_t)NBN * TN * 4);
  float* agg = (float*)alloc((size_t)N * 128 * 4);
  const int NK = TE * N;                       // 150000 keys
  const int NSB = (NK + 4095) / 4096;          // 37 scan blocks
  int* key     = (int*)alloc((size_t)E * 4);
  int* khist   = (int*)alloc((size_t)NK * 4);
  int* koffs   = (int*)alloc((size_t)(NK + 1) * 4);
  int* kcursor = (int*)alloc((size_t)NK * 4);
  int* kpart   = (int*)alloc((size_t)(NSB + 1) * 4);
  int* jmap    = (int*)alloc((size_t)E * 4);
  int4* meta4_e = (int4*)alloc((size_t)E * 16);
  int4* meta4_n = (int4*)alloc((size_t)N * 16);
  bf16_t* slot_buf = (bf16_t*)alloc((size_t)E * 128 * 2);   // 204.8 MB
  (void)ws_size; (void)n_in; (void)out_size;

  // ---- weight packing ----
  pack_w_kernel<<<192, 256, 0, stream>>>(Weh, pW1e, TE, 384, 0, 4);
  pack_w_kernel<<<192, 256, 0, stream>>>(Weh, pW1s, TE, 384, 128, 4);
  pack_w_kernel<<<192, 256, 0, stream>>>(Weh, pW1d, TE, 384, 256, 4);
  pack_w_kernel<<<192, 256, 0, stream>>>(Weo, pWe2, TE, 128, 0, 4);
  pack_w_kernel<<<128, 256, 0, stream>>>(Wnh, pWn1a, TN, 256, 0, 4);
  pack_w_kernel<<<128, 256, 0, stream>>>(Wnh, pWn1b, TN, 256, 128, 4);
  pack_w_kernel<<<128, 256, 0, stream>>>(Wno, pWn2, TN, 128, 0, 4);

  // ---- P precompute (nf read once) ----
  const int ptiles = (N + 63) / 64;
  precompute_p2_kernel<<<ptiles, 256, 0, stream>>>(
      nf, pW1s, pW1d, pWn1b, Ps, Pd, Pn, N);

  // ---- type sorts ----
  count_types_kernel<3><<<NBE, 256, 0, stream>>>(etype, E, blkcnt_e);
  scan_blocks_kernel<3><<<1, 256, 0, stream>>>(blkcnt_e, NBE, blkbase_e);
  write_ranks_kernel<3><<<NBE, 256, 0, stream>>>(etype, E, blkbase_e, rank_e, perm_e);

  count_types_kernel<2><<<NBN, 256, 0, stream>>>(ntype, N, blkcnt_n);
  scan_blocks_kernel<2><<<1, 256, 0, stream>>>(blkcnt_n, NBN, blkbase_n);
  write_ranks_kernel<2><<<NBN, 256, 0, stream>>>(ntype, N, blkbase_n, rank_n, perm_n);

  // ---- (type, dst[j]) slots + pos-ordered meta ----
  hipMemsetAsync(khist, 0, (size_t)NK * 4, stream);
  key_hist_kernel<<<(E + 255) / 256, 256, 0, stream>>>(
      rank_e, dst, blkbase_e, E, N, key, khist);
  mscan_pass1<<<NSB, 1024, 0, stream>>>(khist, NK, kpart);
  mscan_pass2<<<1, 1024, 0, stream>>>(kpart, NSB);
  mscan_pass3<<<NSB, 1024, 0, stream>>>(khist, NK, kpart, NSB, koffs, kcursor);
  build_meta_edge_kernel<<<(E + 255) / 256, 256, 0, stream>>>(
      key, perm_e, rank_e, src, dst, kcursor, meta4_e, jmap, E);

  gather_meta_node_kernel<<<(N + 255) / 256, 256, 0, stream>>>(
      perm_n, rank_n, meta4_n, N);

  float* out_nf = (float*)d_out;                      // new_nf first
  float* out_ef = (float*)d_out + (size_t)N * 128;    // then new_ef

  // ---- edge MLP: seq ef reads (NT), slot_buf writes only (NT) ----
  mlp8nt_kernel<3, true><<<768, 256, 0, stream>>>(
      ef, meta4_e, blkbase_e,
      pW1e, beh, pWe2, beo, Ps, Pd, N, nullptr, slot_buf, E);

  // ---- fused aggregate + scatter (NT streams) ----
  aggregate_scatter_kernel<<<3200, 256, 0, stream>>>(
      slot_buf, koffs, jmap, out_ef, agg, N);

  // ---- node MLP ----
  mlp8nt_kernel<2, false><<<768, 256, 0, stream>>>(
      agg, meta4_n, blkbase_n,
      pWn1a, bnh, pWn2, bno, Pn, nullptr, N, out_nf, nullptr, N);
}

// Round 13
// 745.715 us; speedup vs baseline: 1.2501x; 1.2501x over previous
//
#include <hip/hip_runtime.h>

typedef __bf16 bf16_t;
typedef bf16_t bf16x2_t __attribute__((ext_vector_type(2)));
typedef bf16_t bf16x8_t __attribute__((ext_vector_type(8)));
typedef float  f32x4_t  __attribute__((ext_vector_type(4)));

#define RCHUNK 4096
#define MFMA16(a, b, c) __builtin_amdgcn_mfma_f32_16x16x32_bf16((a), (b), (c), 0, 0, 0)

// ---------------------------------------------------------------------------
// Weight packing: W[t][k0+k][n] (f32, row-stride 128) -> bf16 MFMA-B-fragment
// order: out[((t*KB+kb)*8+nb)*512 + l*8 + j] = W[t][k0+kb*32+(l>>4)*8+j][nb*16+(l&15)]
// ---------------------------------------------------------------------------
__global__ void pack_w_kernel(const float* __restrict__ W, bf16_t* __restrict__ out,
                              int T, int Ksrc, int k0, int KB)
{
  int total = T * KB * 8 * 512;
  for (int idx = blockIdx.x * blockDim.x + threadIdx.x; idx < total;
       idx += gridDim.x * blockDim.x) {
    int j  = idx & 7;
    int l  = (idx >> 3) & 63;
    int nb = (idx >> 9) & 7;
    int r  = idx >> 12;
    int kb = r % KB;
    int t  = r / KB;
    int k = k0 + kb * 32 + ((l >> 4) << 3) + j;
    int n = nb * 16 + (l & 15);
    out[idx] = (bf16_t)W[((size_t)t * Ksrc + k) * 128 + n];
  }
}

// ---------------------------------------------------------------------------
// Stable counting-sort rank/perm over a small type alphabet T.
// ---------------------------------------------------------------------------
template <int T>
__global__ void count_types_kernel(const int* __restrict__ tv, int n,
                                   int* __restrict__ blkcnt)
{
  __shared__ int cnt[T];
  int tid = threadIdx.x, b = blockIdx.x;
  if (tid < T) cnt[tid] = 0;
  __syncthreads();
  int lo = b * RCHUNK, hi = min(n, lo + RCHUNK);
  int loc[T];
#pragma unroll
  for (int t = 0; t < T; ++t) loc[t] = 0;
  for (int i = lo + tid; i < hi; i += 256) {
    int tq = tv[i];
#pragma unroll
    for (int t = 0; t < T; ++t) loc[t] += (tq == t);
  }
#pragma unroll
  for (int t = 0; t < T; ++t)
    if (loc[t]) atomicAdd(&cnt[t], loc[t]);
  __syncthreads();
  if (tid < T) blkcnt[b * T + tid] = cnt[tid];
}

template <int T>
__global__ void scan_blocks_kernel(const int* __restrict__ blkcnt, int nblocks,
                                   int* __restrict__ blkbase)
{
  __shared__ int sh[256];
  __shared__ int tot[T];
  int tid = threadIdx.x;
  int myc[T], excl[T];
#pragma unroll
  for (int t = 0; t < T; ++t) myc[t] = (tid < nblocks) ? blkcnt[tid * T + t] : 0;
#pragma unroll
  for (int t = 0; t < T; ++t) {
    sh[tid] = myc[t];
    __syncthreads();
    for (int off = 1; off < 256; off <<= 1) {
      int v = (tid >= off) ? sh[tid - off] : 0;
      __syncthreads();
      sh[tid] += v;
      __syncthreads();
    }
    excl[t] = sh[tid] - myc[t];
    if (tid == 255) tot[t] = sh[255];
    __syncthreads();
  }
  if (tid < nblocks) {
    int run = 0;
#pragma unroll
    for (int t = 0; t < T; ++t) {
      blkbase[tid * T + t] = run + excl[t];
      run += tot[t];
    }
  }
}

template <int T>
__global__ void write_ranks_kernel(const int* __restrict__ tv, int n,
                                   const int* __restrict__ blkbase,
                                   int* __restrict__ rank, int* __restrict__ perm)
{
  __shared__ int sh[256];
  int tid = threadIdx.x, b = blockIdx.x;
  int lo = b * RCHUNK + tid * 16;
  int tvq[16];
  int myc[T];
#pragma unroll
  for (int t = 0; t < T; ++t) myc[t] = 0;
#pragma unroll
  for (int q = 0; q < 16; ++q) {
    int i = lo + q;
    int tq = (i < n) ? tv[i] : -1;
    tvq[q] = tq;
#pragma unroll
    for (int t = 0; t < T; ++t) myc[t] += (tq == t);
  }
  int mybase[T];
#pragma unroll
  for (int t = 0; t < T; ++t) {
    sh[tid] = myc[t];
    __syncthreads();
    for (int off = 1; off < 256; off <<= 1) {
      int v = (tid >= off) ? sh[tid - off] : 0;
      __syncthreads();
      sh[tid] += v;
      __syncthreads();
    }
    mybase[t] = blkbase[b * T + t] + sh[tid] - myc[t];
    __syncthreads();
  }
#pragma unroll
  for (int q = 0; q < 16; ++q) {
    int tq = tvq[q];
    if (tq < 0) continue;
    int r = 0;
#pragma unroll
    for (int t = 0; t < T; ++t)
      if (tq == t) { r = mybase[t]; mybase[t] = r + 1; }
    rank[lo + q] = r;
    perm[r] = lo + q;
  }
}

// ---------------------------------------------------------------------------
// (type, dst[j]) keys: key[pos] = t(pos)*N + dst[rank[pos]]; multi-block scan;
// meta built in SLOT order: meta4[slot] = {e, src[e], dst[e], j};
// dstj[slot] = dst[rank[pos]]  (the aggregation key, contiguous in slot order)
// ---------------------------------------------------------------------------
__global__ void key_hist_kernel(const int* __restrict__ rank,
                                const int* __restrict__ dst,
                                const int* __restrict__ tb, int E, int Nn,
                                int* __restrict__ key, int* __restrict__ khist)
{
  int pos = blockIdx.x * blockDim.x + threadIdx.x;
  if (pos < E) {
    int t = (pos >= tb[1]) + (pos >= tb[2]);
    int k = t * Nn + dst[rank[pos]];
    key[pos] = k;
    atomicAdd(&khist[k], 1);
  }
}

__global__ __launch_bounds__(1024) void mscan_pass1(const int* __restrict__ h,
                                                    int n, int* __restrict__ part)
{
  __shared__ int sh[1024];
  int tid = threadIdx.x;
  int i0 = blockIdx.x * 4096 + tid * 4;
  int s = 0;
#pragma unroll
  for (int q = 0; q < 4; ++q) { int i = i0 + q; s += (i < n) ? h[i] : 0; }
  sh[tid] = s;
  __syncthreads();
  for (int off = 512; off > 0; off >>= 1) {
    if (tid < off) sh[tid] += sh[tid + off];
    __syncthreads();
  }
  if (tid == 0) part[blockIdx.x] = sh[0];
}

__global__ __launch_bounds__(1024) void mscan_pass2(int* __restrict__ part, int nb)
{
  __shared__ int sh[1024];
  int tid = threadIdx.x;
  int v = (tid < nb) ? part[tid] : 0;
  sh[tid] = v;
  __syncthreads();
  for (int off = 1; off < 1024; off <<= 1) {
    int u = (tid >= off) ? sh[tid - off] : 0;
    __syncthreads();
    sh[tid] += u;
    __syncthreads();
  }
  if (tid < nb) part[tid] = sh[tid] - v;
  if (tid == 1023) part[nb] = sh[1023];
}

__global__ __launch_bounds__(1024) void mscan_pass3(
    const int* __restrict__ h, int n, const int* __restrict__ part, int nb,
    int* __restrict__ offs, int* __restrict__ cur)
{
  __shared__ int sh[1024];
  int tid = threadIdx.x;
  int i0 = blockIdx.x * 4096 + tid * 4;
  int v[4];
  int s = 0;
#pragma unroll
  for (int q = 0; q < 4; ++q) { int i = i0 + q; v[q] = (i < n) ? h[i] : 0; s += v[q]; }
  sh[tid] = s;
  __syncthreads();
  for (int off = 1; off < 1024; off <<= 1) {
    int u = (tid >= off) ? sh[tid - off] : 0;
    __syncthreads();
    sh[tid] += u;
    __syncthreads();
  }
  int run = part[blockIdx.x] + sh[tid] - s;
#pragma unroll
  for (int q = 0; q < 4; ++q) {
    int i = i0 + q;
    if (i < n) { offs[i] = run; cur[i] = run; run += v[q]; }
  }
  if (blockIdx.x == 0 && tid == 0) offs[n] = part[nb];
}

__global__ void build_meta_slot_kernel(const int* __restrict__ key,
                                       const int* __restrict__ perm,
                                       const int* __restrict__ rank,
                                       const int* __restrict__ src,
                                       const int* __restrict__ dst,
                                       int* __restrict__ kcursor,
                                       int4* __restrict__ meta4,
                                       int* __restrict__ dstj, int E)
{
  int pos = blockIdx.x * blockDim.x + threadIdx.x;
  if (pos < E) {
    int slot = atomicAdd(&kcursor[key[pos]], 1);
    int e = perm[pos];
    int j = rank[pos];
    int4 m;
    m.x = e; m.y = src[e]; m.z = dst[e]; m.w = j;
    meta4[slot] = m;
    dstj[slot] = dst[j];       // aggregation key (contiguous in slot order)
  }
}

__global__ void gather_meta_node_kernel(const int* __restrict__ perm,
                                        const int* __restrict__ rank,
                                        int4* __restrict__ meta4, int N)
{
  int i = blockIdx.x * blockDim.x + threadIdx.x;
  if (i < N) {
    int e = perm[i];
    int4 m;
    m.x = e; m.y = e; m.z = e; m.w = rank[i];
    meta4[i] = m;
  }
}

// ---------------------------------------------------------------------------
// P precompute: one block per 64-node tile computes ALL 8 projections.
// ---------------------------------------------------------------------------
__global__ __launch_bounds__(256, 4) void precompute_p2_kernel(
    const float* __restrict__ nf,
    const bf16_t* __restrict__ pW1s, const bf16_t* __restrict__ pW1d,
    const bf16_t* __restrict__ pWn1b,
    bf16_t* __restrict__ Ps, bf16_t* __restrict__ Pd, bf16_t* __restrict__ Pn,
    int Nn)
{
  __shared__ char Ysm[16384];
  const int tid = threadIdx.x, l = tid & 63, w = tid >> 6;
  const int rb = (w >> 1) * 32, cb = (w & 1) * 64, l15 = l & 15;
  const int koff = (l >> 4) << 3;
  const int base = blockIdx.x * 64;

  const int r0 = min(base + rb + l15, Nn - 1);
  const int r1 = min(base + rb + l15 + 16, Nn - 1);
  const float* q0 = nf + (size_t)r0 * 128 + koff;
  const float* q1 = nf + (size_t)r1 * 128 + koff;
  bf16x8_t a0[4], a1[4];
#pragma unroll
  for (int kb = 0; kb < 4; ++kb) {
    f32x4_t u0 = ((const f32x4_t*)(q0 + kb * 32))[0];
    f32x4_t u1 = ((const f32x4_t*)(q0 + kb * 32))[1];
    f32x4_t u2 = ((const f32x4_t*)(q1 + kb * 32))[0];
    f32x4_t u3 = ((const f32x4_t*)(q1 + kb * 32))[1];
#pragma unroll
    for (int z = 0; z < 4; ++z) {
      a0[kb][z] = (bf16_t)u0[z]; a0[kb][4 + z] = (bf16_t)u1[z];
      a1[kb][z] = (bf16_t)u2[z]; a1[kb][4 + z] = (bf16_t)u3[z];
    }
  }

  for (int which = 0; which < 8; ++which) {
    const bf16_t* pB; bf16_t* po;
    if (which < 3)      { pB = pW1s + which * 16384;        po = Ps + (size_t)which * Nn * 128; }
    else if (which < 6) { pB = pW1d + (which - 3) * 16384;  po = Pd + (size_t)(which - 3) * Nn * 128; }
    else                { pB = pWn1b + (which - 6) * 16384; po = Pn + (size_t)(which - 6) * Nn * 128; }
    const bf16x8_t* wg = (const bf16x8_t*)pB;

    f32x4_t acc[2][4];
#pragma unroll
    for (int m = 0; m < 2; ++m)
#pragma unroll
      for (int n = 0; n < 4; ++n) acc[m][n] = (f32x4_t){0.f, 0.f, 0.f, 0.f};
#pragma unroll
    for (int kb = 0; kb < 4; ++kb) {
      bf16x8_t bfr[4];
#pragma unroll
      for (int n = 0; n < 4; ++n)
        bfr[n] = wg[(size_t)((kb * 8 + (cb >> 4) + n) * 64 + l)];
#pragma unroll
      for (int n = 0; n < 4; ++n) {
        acc[0][n] = MFMA16(a0[kb], bfr[n], acc[0][n]);
        acc[1][n] = MFMA16(a1[kb], bfr[n], acc[1][n]);
      }
    }

    __syncthreads();
#pragma unroll
    for (int n = 0; n < 4; ++n) {
      int col = cb + 16 * n + l15;
#pragma unroll
      for (int m = 0; m < 2; ++m)
#pragma unroll
        for (int jj = 0; jj < 4; ++jj) {
          int row = rb + 16 * m + ((l >> 4) << 2) + jj;
          *(bf16_t*)(Ysm + row * 256 + ((col * 2) ^ ((row & 7) << 4))) =
              (bf16_t)acc[m][n][jj];
        }
    }
    __syncthreads();
    {
      int row = tid >> 2, cpart = tid & 3;
      int node = base + row;
      if (node < Nn) {
        bf16_t* dstp = po + (size_t)node * 128 + cpart * 32;
#pragma unroll
        for (int q = 0; q < 4; ++q) {
          int c = cpart * 4 + q;
          *(uint4*)(dstp + q * 8) = *(const uint4*)(
              Ysm + row * 256 + ((c * 16) ^ ((row & 7) << 4)));
        }
      }
    }
  }
}

// ---------------------------------------------------------------------------
// mlp10: fused per-type 2-layer MLP over single-type 64-row tiles in SLOT
// order ((type,dst[j])-sorted). Per tile: y -> out[j] (f32 scatter), y (bf16)
// staged in Hsm, then per-column RUN REDUCTION over the tile's contiguous
// dst[j]-runs with ONE unsafeAtomicAdd per (run, column) into agg.
// NODE: pos order, f32 out[j] scatter only.
// W1 in LDS, W2 in regs; Psum staged IN-PLACE into Hsm; LDS 50KB, 3 blk/CU.
// ---------------------------------------------------------------------------
template <int T, bool EDGE>
__global__ __launch_bounds__(256, 3) void mlp10_kernel(
    const float* __restrict__ feat,
    const int4* __restrict__ meta4,
    const int* __restrict__ dstj,
    const int* __restrict__ tbase,
    const bf16_t* __restrict__ pW1, const float* __restrict__ b1,
    const bf16_t* __restrict__ pW2, const float* __restrict__ b2,
    const bf16_t* __restrict__ P1, const bf16_t* __restrict__ P2, int pnodes,
    float* __restrict__ out, float* __restrict__ agg_out, int Ntot)
{
  __shared__ char Wsm[32768];
  __shared__ char Hsm[16384];
  __shared__ int sm_e[64], sm_sl[64], sm_s0[64], sm_s1[64], sm_key[64];

  const int tid = threadIdx.x;
  const int l = tid & 63, w = tid >> 6;
  const int rb = (w >> 1) * 32, cb = (w & 1) * 64;
  const int l15 = l & 15;
  const int koff = (l >> 4) << 3;

  const int s0 = tbase[0];
  const int s1 = (T > 1) ? tbase[1] : Ntot;
  const int s2 = (T > 2) ? tbase[2] : Ntot;
  const int e0t = (T > 1) ? s1 : Ntot;
  const int e1t = (T > 2) ? s2 : Ntot;
  const int c0 = (e0t - s0 + 63) >> 6;
  const int c1 = (T > 1) ? ((e1t - s1 + 63) >> 6) : 0;
  const int c2 = (T > 2) ? ((Ntot - s2 + 63) >> 6) : 0;
  const int cum1 = c0, cum2 = c0 + c1, total = cum2 + c2;

  const int tpb = (total + gridDim.x - 1) / gridDim.x;
  const int pt0 = blockIdx.x * tpb;
  const int pt1 = min(total, pt0 + tpb);

  int cur_t = -1;
  bf16x8_t w2r[16];
  float bh[4], bo[4];

  for (int pt = pt0; pt < pt1; ++pt) {
    const int t = (pt < cum1) ? 0 : ((pt < cum2) ? 1 : 2);
    const int tstart = (t == 0) ? s0 : ((t == 1) ? s1 : s2);
    const int tend = (t == 0) ? e0t : ((t == 1) ? e1t : Ntot);
    const int i = pt - ((t == 0) ? 0 : ((t == 1) ? cum1 : cum2));
    const int pbase = tstart + (i << 6);

    __syncthreads();                   // B0: prev tile (incl. reduction) done
    if (tid < 64) {
      int pos = pbase + tid;
      if (pos < tend) {
        int4 m = meta4[pos];
        sm_e[tid] = m.x;
        sm_sl[tid] = m.w;              // j (final output row)
        if (EDGE) { sm_s0[tid] = m.y; sm_s1[tid] = m.z; sm_key[tid] = dstj[pos]; }
      } else {
        sm_e[tid] = 0; sm_sl[tid] = -1;
        if (EDGE) { sm_s0[tid] = 0; sm_s1[tid] = 0; sm_key[tid] = -1; }
      }
    }
    __syncthreads();                   // B1: meta visible

    // ---- burst A: lane's full-K slice of 2 rows ----
    const int ar0 = rb + l15, ar1 = ar0 + 16;
    const float* q0 = feat + (size_t)sm_e[ar0] * 128 + koff;
    const float* q1 = feat + (size_t)sm_e[ar1] * 128 + koff;
    f32x4_t areg[2][4][2];
#pragma unroll
    for (int kb = 0; kb < 4; ++kb) {
      areg[0][kb][0] = ((const f32x4_t*)(q0 + kb * 32))[0];
      areg[0][kb][1] = ((const f32x4_t*)(q0 + kb * 32))[1];
      areg[1][kb][0] = ((const f32x4_t*)(q1 + kb * 32))[0];
      areg[1][kb][1] = ((const f32x4_t*)(q1 + kb * 32))[1];
    }

    // ---- Psum gather -> Hsm IN-PLACE (XOR byte swizzle) ----
#pragma unroll
    for (int q = 0; q < 4; ++q) {
      int idx = tid * 4 + q;
      int row = idx >> 4, c8 = idx & 15;
      bf16x8_t s;
      if (EDGE) {
        bf16x8_t u = ((const bf16x8_t*)(P1 + ((size_t)t * pnodes + sm_s0[row]) * 128))[c8];
        bf16x8_t v = ((const bf16x8_t*)(P2 + ((size_t)t * pnodes + sm_s1[row]) * 128))[c8];
#pragma unroll
        for (int z = 0; z < 8; ++z) s[z] = (bf16_t)((float)u[z] + (float)v[z]);
      } else {
        s = ((const bf16x8_t*)(P1 + ((size_t)t * pnodes + sm_e[row]) * 128))[c8];
      }
      *(bf16x8_t*)(Hsm + row * 256 + ((c8 << 4) ^ ((row & 7) << 4))) = s;
    }

    if (t != cur_t) {
      __syncthreads();                 // no wave still reading old Wsm
      {
        const uint4* g = (const uint4*)(pW1 + (size_t)t * 16384);
        uint4* d = (uint4*)Wsm;
#pragma unroll
        for (int q = 0; q < 8; ++q) d[q * 256 + tid] = g[q * 256 + tid];
      }
      {
        const bf16x8_t* g2 = (const bf16x8_t*)pW2;
#pragma unroll
        for (int kb = 0; kb < 4; ++kb)
#pragma unroll
          for (int n = 0; n < 4; ++n)
            w2r[kb * 4 + n] = g2[(size_t)((t * 4 + kb) * 8 + (cb >> 4) + n) * 64 + l];
      }
#pragma unroll
      for (int n = 0; n < 4; ++n) {
        bh[n] = b1[t * 128 + cb + 16 * n + l15];
        bo[n] = b2[t * 128 + cb + 16 * n + l15];
      }
      cur_t = t;
      __syncthreads();
    }

    // ---------------- layer 1 (W1 from LDS) ----------------
    f32x4_t acc[2][4];
#pragma unroll
    for (int m = 0; m < 2; ++m)
#pragma unroll
      for (int n = 0; n < 4; ++n) acc[m][n] = (f32x4_t){0.f, 0.f, 0.f, 0.f};

#pragma unroll
    for (int kb = 0; kb < 4; ++kb) {
      bf16x8_t bfr[4];
#pragma unroll
      for (int n = 0; n < 4; ++n)
        bfr[n] = *(const bf16x8_t*)(Wsm + ((kb * 8 + (cb >> 4) + n) * 64 + l) * 16);
      bf16x8_t a0, a1;
#pragma unroll
      for (int z = 0; z < 4; ++z) {
        a0[z] = (bf16_t)areg[0][kb][0][z]; a0[4 + z] = (bf16_t)areg[0][kb][1][z];
        a1[z] = (bf16_t)areg[1][kb][0][z]; a1[4 + z] = (bf16_t)areg[1][kb][1][z];
      }
#pragma unroll
      for (int n = 0; n < 4; ++n) {
        acc[0][n] = MFMA16(a0, bfr[n], acc[0][n]);
        acc[1][n] = MFMA16(a1, bfr[n], acc[1][n]);
      }
    }

    __syncthreads();                   // B3: Psum staged in Hsm visible
    // h = relu(acc + Psum + b1), in place in Hsm
#pragma unroll
    for (int n = 0; n < 4; ++n) {
      int col = cb + 16 * n + l15;
      int byte = col * 2;
#pragma unroll
      for (int m = 0; m < 2; ++m)
#pragma unroll
        for (int jj = 0; jj < 4; ++jj) {
          int row = rb + 16 * m + ((l >> 4) << 2) + jj;
          char* addr = Hsm + row * 256 + (byte ^ ((row & 7) << 4));
          float pv = (float)*(const bf16_t*)addr;
          float v = acc[m][n][jj] + pv + bh[n];
          v = v > 0.f ? v : 0.f;
          *(bf16_t*)addr = (bf16_t)v;
        }
    }
    __syncthreads();                   // B4: Hsm complete

    // ---------------- layer 2 (W2 in regs) ----------------
    f32x4_t acc2[2][4];
#pragma unroll
    for (int m = 0; m < 2; ++m)
#pragma unroll
      for (int n = 0; n < 4; ++n) acc2[m][n] = (f32x4_t){0.f, 0.f, 0.f, 0.f};

#pragma unroll
    for (int kb = 0; kb < 4; ++kb) {
      int kbyte = kb * 64 + ((l >> 4) << 4);
      int row0 = rb + l15, row1 = row0 + 16;
      bf16x8_t h0 = *(const bf16x8_t*)(Hsm + row0 * 256 + (kbyte ^ ((row0 & 7) << 4)));
      bf16x8_t h1 = *(const bf16x8_t*)(Hsm + row1 * 256 + (kbyte ^ ((row1 & 7) << 4)));
#pragma unroll
      for (int n = 0; n < 4; ++n) {
        acc2[0][n] = MFMA16(h0, w2r[kb * 4 + n], acc2[0][n]);
        acc2[1][n] = MFMA16(h1, w2r[kb * 4 + n], acc2[1][n]);
      }
    }

    // ---------------- epilogue: f32 out[j] scatter ----------------
#pragma unroll
    for (int n = 0; n < 4; ++n) {
      int col = cb + 16 * n + l15;
#pragma unroll
      for (int m = 0; m < 2; ++m)
#pragma unroll
        for (int jj = 0; jj < 4; ++jj) {
          int row = rb + 16 * m + ((l >> 4) << 2) + jj;
          int j = sm_sl[row];
          if (j >= 0) out[(size_t)j * 128 + col] = acc2[m][n][jj] + bo[n];
        }
    }

    if (EDGE) {
      __syncthreads();                 // B5: layer-2 Hsm reads done
      // stage y (bf16) into Hsm for the run reduction
#pragma unroll
      for (int n = 0; n < 4; ++n) {
        int col = cb + 16 * n + l15;
#pragma unroll
        for (int m = 0; m < 2; ++m)
#pragma unroll
          for (int jj = 0; jj < 4; ++jj) {
            int row = rb + 16 * m + ((l >> 4) << 2) + jj;
            *(bf16_t*)(Hsm + row * 256 + ((col * 2) ^ ((row & 7) << 4))) =
                (bf16_t)(acc2[m][n][jj] + bo[n]);
          }
      }
      __syncthreads();                 // B6: y staged
      // per-column dst[j]-run reduction; one atomicAdd per (run, col, half)
      {
        int c = tid & 127, h = tid >> 7;
        int byte = c * 2;
        int cur = -1;
        float s = 0.f;
#pragma unroll 8
        for (int r = 0; r < 32; ++r) {
          int row = (h << 5) + r;
          int k = sm_key[row];
          if (k != cur) {
            if (cur >= 0)
              unsafeAtomicAdd(agg_out + (size_t)cur * 128 + c, s);
            s = 0.f;
            cur = k;
          }
          if (k >= 0)
            s += (float)*(const bf16_t*)(Hsm + row * 256 + (byte ^ ((row & 7) << 4)));
        }
        if (cur >= 0)
          unsafeAtomicAdd(agg_out + (size_t)cur * 128 + c, s);
      }
    }
  }
}

// ---------------------------------------------------------------------------
extern "C" void kernel_launch(void* const* d_in, const int* in_sizes, int n_in,
                              void* d_out, int out_size, void* d_ws, size_t ws_size,
                              hipStream_t stream)
{
  const float* nf    = (const float*)d_in[0];
  const float* ef    = (const float*)d_in[1];
  const int*   src   = (const int*)d_in[2];
  const int*   dst   = (const int*)d_in[3];
  const int*   etype = (const int*)d_in[4];
  const int*   ntype = (const int*)d_in[5];
  const float* Weh   = (const float*)d_in[6];
  const float* beh   = (const float*)d_in[7];
  const float* Weo   = (const float*)d_in[8];
  const float* beo   = (const float*)d_in[9];
  const float* Wnh   = (const float*)d_in[10];
  const float* bnh   = (const float*)d_in[11];
  const float* Wno   = (const float*)d_in[12];
  const float* bno   = (const float*)d_in[13];

  const int E = in_sizes[2];   // 800000
  const int N = in_sizes[5];   // 50000
  const int TE = 3, TN = 2;

  char* ws = (char*)d_ws;
  size_t off = 0;
  auto alloc = [&](size_t bytes) -> char* {
    char* p = ws + off;
    off = (off + bytes + 511) & ~(size_t)511;
    return p;
  };
  bf16_t* pW1e  = (bf16_t*)alloc((size_t)TE * 16384 * 2);
  bf16_t* pW1s  = (bf16_t*)alloc((size_t)TE * 16384 * 2);
  bf16_t* pW1d  = (bf16_t*)alloc((size_t)TE * 16384 * 2);
  bf16_t* pWe2  = (bf16_t*)alloc((size_t)TE * 16384 * 2);
  bf16_t* pWn1a = (bf16_t*)alloc((size_t)TN * 16384 * 2);
  bf16_t* pWn1b = (bf16_t*)alloc((size_t)TN * 16384 * 2);
  bf16_t* pWn2  = (bf16_t*)alloc((size_t)TN * 16384 * 2);
  bf16_t* Ps = (bf16_t*)alloc((size_t)TE * N * 128 * 2);
  bf16_t* Pd = (bf16_t*)alloc((size_t)TE * N * 128 * 2);
  bf16_t* Pn = (bf16_t*)alloc((size_t)TN * N * 128 * 2);
  int* rank_e = (int*)alloc((size_t)E * 4);
  int* perm_e = (int*)alloc((size_t)E * 4);
  int* rank_n = (int*)alloc((size_t)N * 4);
  int* perm_n = (int*)alloc((size_t)N * 4);
  const int NBE = (E + RCHUNK - 1) / RCHUNK;   // 196
  const int NBN = (N + RCHUNK - 1) / RCHUNK;   // 13
  int* blkcnt_e  = (int*)alloc((size_t)NBE * TE * 4);
  int* blkbase_e = (int*)alloc((size_t)NBE * TE * 4);
  int* blkcnt_n  = (int*)alloc((size_t)NBN * TN * 4);
  int* blkbase_n = (int*)alloc((size_t)NBN * TN * 4);
  float* agg = (float*)alloc((size_t)N * 128 * 4);
  const int NK = TE * N;                       // 150000 keys
  const int NSB = (NK + 4095) / 4096;          // 37 scan blocks
  int* key     = (int*)alloc((size_t)E * 4);
  int* khist   = (int*)alloc((size_t)NK * 4);
  int* koffs   = (int*)alloc((size_t)(NK + 1) * 4);
  int* kcursor = (int*)alloc((size_t)NK * 4);
  int* kpart   = (int*)alloc((size_t)(NSB + 1) * 4);
  int* dstj    = (int*)alloc((size_t)E * 4);
  int4* meta4_e = (int4*)alloc((size_t)E * 16);
  int4* meta4_n = (int4*)alloc((size_t)N * 16);
  (void)ws_size; (void)n_in; (void)out_size;

  // ---- weight packing ----
  pack_w_kernel<<<192, 256, 0, stream>>>(Weh, pW1e, TE, 384, 0, 4);
  pack_w_kernel<<<192, 256, 0, stream>>>(Weh, pW1s, TE, 384, 128, 4);
  pack_w_kernel<<<192, 256, 0, stream>>>(Weh, pW1d, TE, 384, 256, 4);
  pack_w_kernel<<<192, 256, 0, stream>>>(Weo, pWe2, TE, 128, 0, 4);
  pack_w_kernel<<<128, 256, 0, stream>>>(Wnh, pWn1a, TN, 256, 0, 4);
  pack_w_kernel<<<128, 256, 0, stream>>>(Wnh, pWn1b, TN, 256, 128, 4);
  pack_w_kernel<<<128, 256, 0, stream>>>(Wno, pWn2, TN, 128, 0, 4);

  // ---- P precompute (nf read once) ----
  const int ptiles = (N + 63) / 64;
  precompute_p2_kernel<<<ptiles, 256, 0, stream>>>(
      nf, pW1s, pW1d, pWn1b, Ps, Pd, Pn, N);

  // ---- type sorts ----
  count_types_kernel<3><<<NBE, 256, 0, stream>>>(etype, E, blkcnt_e);
  scan_blocks_kernel<3><<<1, 256, 0, stream>>>(blkcnt_e, NBE, blkbase_e);
  write_ranks_kernel<3><<<NBE, 256, 0, stream>>>(etype, E, blkbase_e, rank_e, perm_e);

  count_types_kernel<2><<<NBN, 256, 0, stream>>>(ntype, N, blkcnt_n);
  scan_blocks_kernel<2><<<1, 256, 0, stream>>>(blkcnt_n, NBN, blkbase_n);
  write_ranks_kernel<2><<<NBN, 256, 0, stream>>>(ntype, N, blkbase_n, rank_n, perm_n);

  // ---- (type, dst[j]) slots + slot-ordered meta + dstj ----
  hipMemsetAsync(khist, 0, (size_t)NK * 4, stream);
  key_hist_kernel<<<(E + 255) / 256, 256, 0, stream>>>(
      rank_e, dst, blkbase_e, E, N, key, khist);
  mscan_pass1<<<NSB, 1024, 0, stream>>>(khist, NK, kpart);
  mscan_pass2<<<1, 1024, 0, stream>>>(kpart, NSB);
  mscan_pass3<<<NSB, 1024, 0, stream>>>(khist, NK, kpart, NSB, koffs, kcursor);
  build_meta_slot_kernel<<<(E + 255) / 256, 256, 0, stream>>>(
      key, perm_e, rank_e, src, dst, kcursor, meta4_e, dstj, E);

  gather_meta_node_kernel<<<(N + 255) / 256, 256, 0, stream>>>(
      perm_n, rank_n, meta4_n, N);

  float* out_nf = (float*)d_out;                      // new_nf first
  float* out_ef = (float*)d_out + (size_t)N * 128;    // then new_ef

  // ---- zero agg (edge kernel accumulates into it) ----
  hipMemsetAsync(agg, 0, (size_t)N * 128 * 4, stream);

  // ---- edge MLP (slot order): out_ef scatter + fused run-reduced agg ----
  mlp10_kernel<3, true><<<768, 256, 0, stream>>>(
      ef, meta4_e, dstj, blkbase_e,
      pW1e, beh, pWe2, beo, Ps, Pd, N, out_ef, agg, E);

  // ---- node MLP ----
  mlp10_kernel<2, false><<<768, 256, 0, stream>>>(
      agg, meta4_n, nullptr, blkbase_n,
      pWn1a, bnh, pWn2, bno, Pn, nullptr, N, out_nf, nullptr, N);
}